// Round 1
// baseline (1495.026 us; speedup 1.0000x reference)
//
#include <hip/hip_runtime.h>

#define TT 128
#define BB 256
#define KC 64
#define DZ 32
#define DY 16

// ---- output layout (float offsets), reference return order ----
#define OFF_MUP   ((size_t)0)
#define OFF_SIGP  (OFF_MUP  + (size_t)TT*BB*DZ)
#define OFF_MUF   (OFF_SIGP + (size_t)TT*BB*DZ*DZ)
#define OFF_SIGF  (OFF_MUF  + (size_t)TT*BB*DZ)
#define OFF_ALPHA (OFF_SIGF + (size_t)TT*BB*DZ*DZ)
#define OFF_AS    (OFF_ALPHA+ (size_t)TT*BB*KC)
#define OFF_BS    (OFF_AS   + (size_t)TT*BB*DZ*DZ)
#define OFF_CS    (OFF_BS   + (size_t)TT*BB*DZ)

__device__ __forceinline__ float wave_max64(float v) {
#pragma unroll
  for (int o = 32; o > 0; o >>= 1) v = fmaxf(v, __shfl_xor(v, o, 64));
  return v;
}
__device__ __forceinline__ float wave_sum64(float v) {
#pragma unroll
  for (int o = 32; o > 0; o >>= 1) v += __shfl_xor(v, o, 64);
  return v;
}

// ============================================================
// Kernel 1: alpha recursion (independent of Kalman state).
// 1 wave per batch element; lane k = cluster k.
// alphas[t,b,:] written to output; beta0 (=softmax(d0)) to ws.
// ============================================================
__global__ __launch_bounds__(64) void alpha_kernel(const float* __restrict__ dist,
                                                   float* __restrict__ alphas,
                                                   float* __restrict__ beta0) {
  const int b = blockIdx.x;
  const int k = threadIdx.x;
  const float* db = dist + (size_t)b * TT * KC;

  float d0 = db[k];
  float m0 = wave_max64(d0);
  float e0 = expf(d0 - m0);
  float s0 = wave_sum64(e0);
  float carry = e0 / s0;                // beta_0 = softmax(d_0)
  beta0[b * KC + k] = carry;

  for (int t = 0; t < TT; ++t) {
    float d = db[t * KC + k];
    float mm = wave_max64(d);
    float ee = expf(d - mm);
    float ss = wave_sum64(ee);
    float p = (ee / ss) * carry;        // softmax(d_t) * alpha_prev
    float ps = wave_sum64(p);
    float a = p / ps;
    alphas[((size_t)t * BB + b) * KC + k] = a;
    carry = a;
  }
}

// ============================================================
// Kernel 2: batched cluster mixing for all (t,b):
//   As[t,b] = sum_k alpha[t,b,k] A[k]      (uses alpha_t)
//   Bs[t,b] = sum_k alpha[t,b,k] Bm[k]
//   Cs[t,b] = sum_k beta [t,b,k] C[k]      (beta_t = alpha_{t-1}, beta_0 from ws)
// 32 (t,b)-rows per block; alpha/beta rows are wave-uniform -> scalar loads.
// ============================================================
__global__ __launch_bounds__(256) void mix_kernel(const float* __restrict__ A,
                                                  const float* __restrict__ Bm,
                                                  const float* __restrict__ C,
                                                  const float* __restrict__ alphas,
                                                  const float* __restrict__ beta0,
                                                  float* __restrict__ As,
                                                  float* __restrict__ Bs,
                                                  float* __restrict__ Cs) {
  const int g   = blockIdx.x;
  const int t   = g >> 3;            // 8 blocks per t (256 b / 32 rows)
  const int b0  = (g & 7) << 5;      // 32 rows
  const int tid = threadIdx.x;
  const float* arow = alphas + ((size_t)t * BB + b0) * KC;
  const float* brow = (t > 0) ? (alphas + ((size_t)(t - 1) * BB + b0) * KC)
                              : (beta0 + (size_t)b0 * KC);
  const size_t rbase = (size_t)t * BB + b0;

  // ---- A mix: 256 float4 columns, all threads ----
  {
    const float4* wp = (const float4*)A;      // [64][256] float4
    for (int ch = 0; ch < 2; ++ch) {
      float4 acc[16];
#pragma unroll
      for (int r = 0; r < 16; ++r) acc[r] = make_float4(0.f, 0.f, 0.f, 0.f);
      for (int kk = 0; kk < KC; ++kk) {
        float4 w = wp[kk * 256 + tid];
#pragma unroll
        for (int r = 0; r < 16; ++r) {
          float a = arow[(ch * 16 + r) * KC + kk];   // uniform -> s_load
          acc[r].x += a * w.x; acc[r].y += a * w.y;
          acc[r].z += a * w.z; acc[r].w += a * w.w;
        }
      }
#pragma unroll
      for (int r = 0; r < 16; ++r)
        ((float4*)(As + (rbase + ch * 16 + r) * (DZ * DZ)))[tid] = acc[r];
    }
  }
  // ---- C mix (beta) on waves 0-1; B mix (alpha) on wave 2 (dup lanes) ----
  if (tid < 128) {
    const float4* wp = (const float4*)C;      // [64][128] float4
    for (int ch = 0; ch < 2; ++ch) {
      float4 acc[16];
#pragma unroll
      for (int r = 0; r < 16; ++r) acc[r] = make_float4(0.f, 0.f, 0.f, 0.f);
      for (int kk = 0; kk < KC; ++kk) {
        float4 w = wp[kk * 128 + tid];
#pragma unroll
        for (int r = 0; r < 16; ++r) {
          float a = brow[(ch * 16 + r) * KC + kk];
          acc[r].x += a * w.x; acc[r].y += a * w.y;
          acc[r].z += a * w.z; acc[r].w += a * w.w;
        }
      }
#pragma unroll
      for (int r = 0; r < 16; ++r)
        ((float4*)(Cs + (rbase + ch * 16 + r) * (DY * DZ)))[tid] = acc[r];
    }
  } else if (tid < 192) {
    const int c = (tid - 128) & 7;            // 8 cols, lanes duplicated (benign)
    const float4* wp = (const float4*)Bm;     // [64][8] float4
    for (int ch = 0; ch < 2; ++ch) {
      float4 acc[16];
#pragma unroll
      for (int r = 0; r < 16; ++r) acc[r] = make_float4(0.f, 0.f, 0.f, 0.f);
      for (int kk = 0; kk < KC; ++kk) {
        float4 w = wp[kk * 8 + c];
#pragma unroll
        for (int r = 0; r < 16; ++r) {
          float a = arow[(ch * 16 + r) * KC + kk];
          acc[r].x += a * w.x; acc[r].y += a * w.y;
          acc[r].z += a * w.z; acc[r].w += a * w.w;
        }
      }
#pragma unroll
      for (int r = 0; r < 16; ++r)
        ((float4*)(Bs + (rbase + ch * 16 + r) * DZ))[c] = acc[r];
    }
  }
}

// ============================================================
// Kernel 3: sequential Kalman recursion. 1 block (256 thr) per batch b.
// State (mu, Sigma) in LDS. Uses Sigma symmetry:
//   PC = Sigma C^T;  S = C PC + R;  solve S X = PC^T -> X = Kg^T (single-wave GJ)
//   Sigma_f = Sigma - Kg PC^T;  Sigma' = A Sigma_f A^T + Q
// ============================================================
__global__ __launch_bounds__(256) void kf_kernel(const float* __restrict__ yin,  // [B][T][16]
                                                 const float* __restrict__ As,   // [T*B][1024]
                                                 const float* __restrict__ Bs,   // [T*B][32]
                                                 const float* __restrict__ Cs,   // [T*B][512]
                                                 float* __restrict__ out) {
  const int b   = blockIdx.x;
  const int tid = threadIdx.x;

  __shared__ float Sig[DZ][36];    // Sigma_pred (carry)
  __shared__ float Sf [DZ][36];    // Sigma_filt
  __shared__ float Mm [DZ][36];    // A_t @ Sigma_f
  __shared__ float At [DZ][36];
  __shared__ float AtT[DZ][36];
  __shared__ float CtT[DZ][24];    // CtT[z][y] = C_t[y][z]
  __shared__ float PCt[DZ][24];    // PCt[z][x] = (Sigma C^T)[z][x]
  __shared__ float PCtT[DY][36];   // PCt^T
  __shared__ float KgT[DY][36];    // Kg^T
  __shared__ float W[DY][52];      // GJ workspace [S | PCt^T]
  __shared__ float mu[DZ], muf[DZ], innov[DY], Bt[DZ], ytl[DY];

  const int i  = tid >> 3;         // 0..31
  const int j0 = (tid & 7) * 4;    // 0,4,..,28

  // init carry
  {
#pragma unroll
    for (int q = 0; q < 4; ++q) Sig[i][j0 + q] = (i == j0 + q) ? 20.0f : 0.0f;
    if (tid < DZ) mu[tid] = 0.0f;
  }
  __syncthreads();

  for (int t = 0; t < TT; ++t) {
    const size_t tb = (size_t)t * BB + b;

    // ---- phase L: stage A_t, C_t, B_t, y_t; store mu_pred / Sigma_pred (carry)
    {
      float4 a4 = *(const float4*)(As + tb * (DZ * DZ) + i * DZ + j0);
      *(float4*)&At[i][j0] = a4;
      AtT[j0 + 0][i] = a4.x; AtT[j0 + 1][i] = a4.y;
      AtT[j0 + 2][i] = a4.z; AtT[j0 + 3][i] = a4.w;
      if (tid < 128) {
        int yy = tid >> 3;
        float4 c4 = *(const float4*)(Cs + tb * (DY * DZ) + yy * DZ + j0);
        CtT[j0 + 0][yy] = c4.x; CtT[j0 + 1][yy] = c4.y;
        CtT[j0 + 2][yy] = c4.z; CtT[j0 + 3][yy] = c4.w;
      } else if (tid < 160) {
        Bt[tid - 128] = Bs[tb * DZ + (tid - 128)];
      } else if (tid < 176) {
        ytl[tid - 160] = yin[((size_t)b * TT + t) * DY + (tid - 160)];
      }
      float4 s4 = *(float4*)&Sig[i][j0];
      *(float4*)(out + OFF_SIGP + tb * (DZ * DZ) + i * DZ + j0) = s4;
      if (tid < DZ) out[OFF_MUP + tb * DZ + tid] = mu[tid];
    }
    __syncthreads();

    // ---- phase 1: PCt = Sigma @ C^T (+ transpose copies), innov
    if (tid < 128) {
      int z = tid >> 2, x0 = (tid & 3) * 4;
      float4 acc = make_float4(0.f, 0.f, 0.f, 0.f);
      for (int w = 0; w < DZ; ++w) {
        float s = Sig[z][w];
        float4 c = *(float4*)&CtT[w][x0];
        acc.x += s * c.x; acc.y += s * c.y; acc.z += s * c.z; acc.w += s * c.w;
      }
      *(float4*)&PCt[z][x0] = acc;
      PCtT[x0 + 0][z] = acc.x; PCtT[x0 + 1][z] = acc.y;
      PCtT[x0 + 2][z] = acc.z; PCtT[x0 + 3][z] = acc.w;
      W[x0 + 0][16 + z] = acc.x; W[x0 + 1][16 + z] = acc.y;
      W[x0 + 2][16 + z] = acc.z; W[x0 + 3][16 + z] = acc.w;
    } else if (tid < 144) {
      int yy = tid - 128;
      float a = ytl[yy];
      for (int z = 0; z < DZ; ++z) a -= CtT[z][yy] * mu[z];
      innov[yy] = a;
    }
    __syncthreads();

    // ---- phase 2: S = C @ PCt + R  -> W left block
    if (tid < 64) {
      int yy = tid >> 2, x0 = (tid & 3) * 4;
      float4 acc = make_float4(0.f, 0.f, 0.f, 0.f);
      for (int z = 0; z < DZ; ++z) {
        float cv = CtT[z][yy];
        float4 pv = *(float4*)&PCt[z][x0];
        acc.x += cv * pv.x; acc.y += cv * pv.y; acc.z += cv * pv.z; acc.w += cv * pv.w;
      }
      if (yy >= x0 && yy < x0 + 4) (&acc.x)[yy - x0] += 0.03f;
      *(float4*)&W[yy][x0] = acc;
    }
    __syncthreads();

    // ---- phase 3: single-wave Gauss-Jordan solve S X = PCt^T  (X = Kg^T)
    // wave 0 only: lockstep => no barriers across the 16 pivots.
    if (tid < 64) {
      const int q  = tid >> 2;   // row 0..15
      const int cg = tid & 3;    // col-group; handles cg, cg+4, cg+8 (12 f4 = 48 cols)
      for (int p = 0; p < 16; ++p) {
        float pinv = 1.0f / W[p][p];
        if (q != p) {
          float mql = W[q][p] * pinv;
#pragma unroll
          for (int rr = 0; rr < 3; ++rr) {
            int c = (cg + rr * 4) * 4;
            float4 pv = *(float4*)&W[p][c];
            float4 qv = *(float4*)&W[q][c];
            qv.x -= mql * pv.x; qv.y -= mql * pv.y;
            qv.z -= mql * pv.z; qv.w -= mql * pv.w;
            *(float4*)&W[q][c] = qv;
          }
        }
      }
      // scale: KgT[y][z] = W[y][16+z] / W[y][y]
#pragma unroll
      for (int rep = 0; rep < 2; ++rep) {
        int job = tid + rep * 64;       // 128 jobs: 16 y x 8 z-groups
        int yy = job >> 3, z0 = (job & 7) * 4;
        float dinv = 1.0f / W[yy][yy];
        float4 v = *(float4*)&W[yy][16 + z0];
        v.x *= dinv; v.y *= dinv; v.z *= dinv; v.w *= dinv;
        *(float4*)&KgT[yy][z0] = v;
      }
    }
    __syncthreads();

    // ---- phase 5: Sigma_f = Sigma - Kg @ PCt^T; mu_f
    {
      float4 acc = *(float4*)&Sig[i][j0];
      for (int yy = 0; yy < DY; ++yy) {
        float kg = KgT[yy][i];
        float4 pv = *(float4*)&PCtT[yy][j0];
        acc.x -= kg * pv.x; acc.y -= kg * pv.y; acc.z -= kg * pv.z; acc.w -= kg * pv.w;
      }
      *(float4*)&Sf[i][j0] = acc;
      *(float4*)(out + OFF_SIGF + tb * (DZ * DZ) + i * DZ + j0) = acc;
      if (tid < DZ) {
        float a = mu[tid];
        for (int yy = 0; yy < DY; ++yy) a += KgT[yy][tid] * innov[yy];
        muf[tid] = a;
      }
    }
    __syncthreads();

    // ---- phase 6: M = A_t @ Sigma_f; store mu_f
    {
      float4 acc = make_float4(0.f, 0.f, 0.f, 0.f);
      for (int k = 0; k < DZ; ++k) {
        float av = At[i][k];
        float4 sv = *(float4*)&Sf[k][j0];
        acc.x += av * sv.x; acc.y += av * sv.y; acc.z += av * sv.z; acc.w += av * sv.w;
      }
      *(float4*)&Mm[i][j0] = acc;
      if (tid < DZ) out[OFF_MUF + tb * DZ + tid] = muf[tid];
    }
    __syncthreads();

    // ---- phase 7: Sigma' = M @ A_t^T + Q (in place); mu' = A_t mu_f + B_t
    {
      float4 acc = make_float4(0.f, 0.f, 0.f, 0.f);
      for (int k = 0; k < DZ; ++k) {
        float mv = Mm[i][k];
        float4 av = *(float4*)&AtT[k][j0];
        acc.x += mv * av.x; acc.y += mv * av.y; acc.z += mv * av.z; acc.w += mv * av.w;
      }
      if (i >= j0 && i < j0 + 4) (&acc.x)[i - j0] += 0.08f;
      *(float4*)&Sig[i][j0] = acc;
      if (tid < DZ) {
        float a = Bt[tid];
        for (int k = 0; k < DZ; ++k) a += At[tid][k] * muf[k];
        mu[tid] = a;
      }
    }
    __syncthreads();
  }
}

extern "C" void kernel_launch(void* const* d_in, const int* in_sizes, int n_in,
                              void* d_out, int out_size, void* d_ws, size_t ws_size,
                              hipStream_t stream) {
  const float* y    = (const float*)d_in[0];
  const float* dist = (const float*)d_in[1];
  const float* A    = (const float*)d_in[2];
  const float* Bm   = (const float*)d_in[3];
  const float* C    = (const float*)d_in[4];
  float* out   = (float*)d_out;
  float* beta0 = (float*)d_ws;   // 256*64 floats = 64 KB scratch

  hipLaunchKernelGGL(alpha_kernel, dim3(BB), dim3(64), 0, stream,
                     dist, out + OFF_ALPHA, beta0);
  hipLaunchKernelGGL(mix_kernel, dim3(TT * BB / 32), dim3(256), 0, stream,
                     A, Bm, C, out + OFF_ALPHA, beta0,
                     out + OFF_AS, out + OFF_BS, out + OFF_CS);
  hipLaunchKernelGGL(kf_kernel, dim3(BB), dim3(256), 0, stream,
                     y, out + OFF_AS, out + OFF_BS, out + OFF_CS, out);
}

// Round 2
// 1294.713 us; speedup vs baseline: 1.1547x; 1.1547x over previous
//
#include <hip/hip_runtime.h>
#include <math.h>

#define TT 128
#define BB 256
#define KC 64
#define DZ 32
#define DY 16

// ---- output layout (float offsets), reference return order ----
#define OFF_MUP   ((size_t)0)
#define OFF_SIGP  (OFF_MUP  + (size_t)TT*BB*DZ)
#define OFF_MUF   (OFF_SIGP + (size_t)TT*BB*DZ*DZ)
#define OFF_SIGF  (OFF_MUF  + (size_t)TT*BB*DZ)
#define OFF_ALPHA (OFF_SIGF + (size_t)TT*BB*DZ*DZ)
#define OFF_AS    (OFF_ALPHA+ (size_t)TT*BB*KC)
#define OFF_BS    (OFF_AS   + (size_t)TT*BB*DZ*DZ)
#define OFF_CS    (OFF_BS   + (size_t)TT*BB*DZ)

// raw barrier: LDS visibility only, no vmcnt drain (verified m201 pattern)
#define BAR() do { asm volatile("s_waitcnt lgkmcnt(0)" ::: "memory"); \
                   __builtin_amdgcn_s_barrier(); \
                   asm volatile("" ::: "memory"); } while (0)

__device__ __forceinline__ float wave_max64(float v) {
#pragma unroll
  for (int o = 32; o > 0; o >>= 1) v = fmaxf(v, __shfl_xor(v, o, 64));
  return v;
}
__device__ __forceinline__ float wave_sum64(float v) {
#pragma unroll
  for (int o = 32; o > 0; o >>= 1) v += __shfl_xor(v, o, 64);
  return v;
}
__device__ __forceinline__ float4 shfl4(const float4& v, int src) {
  return make_float4(__shfl(v.x, src, 64), __shfl(v.y, src, 64),
                     __shfl(v.z, src, 64), __shfl(v.w, src, 64));
}
__device__ __forceinline__ float f4get(const float4& v, int e) {
  return e == 0 ? v.x : (e == 1 ? v.y : (e == 2 ? v.z : v.w));
}

// ============================================================
// Kernel 1: alpha recursion in LOG space (parallel in t).
// alpha_t = softmax_k( ls_0 + sum_{s<=t} ls_s ), ls = log_softmax(d).
// Block = 256 thr (4 waves) per batch b; lane = cluster k.
// Wave w owns the contiguous t-chunk [32w, 32w+32).
// ============================================================
__global__ __launch_bounds__(256) void alpha_kernel(const float* __restrict__ dist,
                                                    float* __restrict__ alphas,
                                                    float* __restrict__ beta0) {
  const int b = blockIdx.x;
  const int w = threadIdx.x >> 6;
  const int lane = threadIdx.x & 63;
  const float* db = dist + (size_t)b * TT * KC;

  __shared__ float ls[TT][KC];     // 32 KB
  __shared__ float chT[4][KC];
  __shared__ float l0[KC];

  // pass 1: log-softmax per t, chunk sums
  float csum = 0.f;
  for (int tt = 0; tt < 32; ++tt) {
    int t = w * 32 + tt;
    float d = db[t * KC + lane];
    float m = wave_max64(d);
    float e = expf(d - m);
    float s = wave_sum64(e);
    float lsv = d - m - logf(s);
    ls[t][lane] = lsv;
    csum += lsv;
    if (t == 0) l0[lane] = lsv;
  }
  chT[w][lane] = csum;
  __syncthreads();

  // pass 2: prefix within chunk, softmax over k per t
  float off = l0[lane];                       // extra softmax(d0) factor
  for (int w2 = 0; w2 < w; ++w2) off += chT[w2][lane];
  if (threadIdx.x < 64) beta0[b * KC + lane] = expf(l0[lane]);

  float run = off;
  for (int tt = 0; tt < 32; ++tt) {
    int t = w * 32 + tt;
    run += ls[t][lane];
    float m = wave_max64(run);
    float e = expf(run - m);
    float s = wave_sum64(e);
    alphas[((size_t)t * BB + b) * KC + lane] = e / s;
  }
}

// ============================================================
// Kernel 2: batched cluster mixing (alpha rows staged in LDS).
// ============================================================
__global__ __launch_bounds__(256) void mix_kernel(const float* __restrict__ A,
                                                  const float* __restrict__ Bm,
                                                  const float* __restrict__ C,
                                                  const float* __restrict__ alphas,
                                                  const float* __restrict__ beta0,
                                                  float* __restrict__ As,
                                                  float* __restrict__ Bs,
                                                  float* __restrict__ Cs) {
  const int g   = blockIdx.x;
  const int t   = g >> 3;
  const int b0  = (g & 7) << 5;
  const int tid = threadIdx.x;
  const float* arow = alphas + ((size_t)t * BB + b0) * KC;
  const float* brow = (t > 0) ? (alphas + ((size_t)(t - 1) * BB + b0) * KC)
                              : (beta0 + (size_t)b0 * KC);
  const size_t rbase = (size_t)t * BB + b0;

  __shared__ float aS[32][KC];
  __shared__ float bS[32][KC];
  ((float4*)aS)[tid]       = ((const float4*)arow)[tid];
  ((float4*)aS)[tid + 256] = ((const float4*)arow)[tid + 256];
  ((float4*)bS)[tid]       = ((const float4*)brow)[tid];
  ((float4*)bS)[tid + 256] = ((const float4*)brow)[tid + 256];
  __syncthreads();

  // ---- A mix ----
  {
    const float4* wp = (const float4*)A;      // [64][256] float4
    for (int ch = 0; ch < 2; ++ch) {
      float4 acc[16];
#pragma unroll
      for (int r = 0; r < 16; ++r) acc[r] = make_float4(0.f, 0.f, 0.f, 0.f);
      for (int kk = 0; kk < KC; ++kk) {
        float4 wv = wp[kk * 256 + tid];
#pragma unroll
        for (int r = 0; r < 16; ++r) {
          float a = aS[ch * 16 + r][kk];
          acc[r].x += a * wv.x; acc[r].y += a * wv.y;
          acc[r].z += a * wv.z; acc[r].w += a * wv.w;
        }
      }
#pragma unroll
      for (int r = 0; r < 16; ++r)
        ((float4*)(As + (rbase + ch * 16 + r) * (DZ * DZ)))[tid] = acc[r];
    }
  }
  // ---- C mix (beta) on waves 0-1; B mix on wave 2 ----
  if (tid < 128) {
    const float4* wp = (const float4*)C;      // [64][128] float4
    for (int ch = 0; ch < 2; ++ch) {
      float4 acc[16];
#pragma unroll
      for (int r = 0; r < 16; ++r) acc[r] = make_float4(0.f, 0.f, 0.f, 0.f);
      for (int kk = 0; kk < KC; ++kk) {
        float4 wv = wp[kk * 128 + tid];
#pragma unroll
        for (int r = 0; r < 16; ++r) {
          float a = bS[ch * 16 + r][kk];
          acc[r].x += a * wv.x; acc[r].y += a * wv.y;
          acc[r].z += a * wv.z; acc[r].w += a * wv.w;
        }
      }
#pragma unroll
      for (int r = 0; r < 16; ++r)
        ((float4*)(Cs + (rbase + ch * 16 + r) * (DY * DZ)))[tid] = acc[r];
    }
  } else if (tid < 192) {
    const int c = (tid - 128) & 7;
    const float4* wp = (const float4*)Bm;     // [64][8] float4
    for (int ch = 0; ch < 2; ++ch) {
      float4 acc[16];
#pragma unroll
      for (int r = 0; r < 16; ++r) acc[r] = make_float4(0.f, 0.f, 0.f, 0.f);
      for (int kk = 0; kk < KC; ++kk) {
        float4 wv = wp[kk * 8 + c];
#pragma unroll
        for (int r = 0; r < 16; ++r) {
          float a = aS[ch * 16 + r][kk];
          acc[r].x += a * wv.x; acc[r].y += a * wv.y;
          acc[r].z += a * wv.z; acc[r].w += a * wv.w;
        }
      }
#pragma unroll
      for (int r = 0; r < 16; ++r)
        ((float4*)(Bs + (rbase + ch * 16 + r) * DZ))[c] = acc[r];
    }
  }
}

// ============================================================
// Kernel 3: sequential Kalman recursion. 1 block (256 thr) per batch.
// Raw barriers (no vmcnt drain), register prefetch of next step's
// A/C/B/y, register-shuffle Gauss-Jordan on wave0.
// ============================================================
__global__ __launch_bounds__(256) void kf_kernel(const float* __restrict__ yin,  // [B][T][16]
                                                 const float* __restrict__ As,   // [T*B][1024]
                                                 const float* __restrict__ Bs,   // [T*B][32]
                                                 const float* __restrict__ Cs,   // [T*B][512]
                                                 float* __restrict__ out) {
  const int b   = blockIdx.x;
  const int tid = threadIdx.x;

  __shared__ float Sig[DZ][36];
  __shared__ float Sf [DZ][36];
  __shared__ float Mm [DZ][36];
  __shared__ float At [DZ][36];
  __shared__ float AtT[DZ][36];
  __shared__ float CtT[DZ][24];    // CtT[z][y] = C_t[y][z]
  __shared__ float PCt[DZ][24];    // (Sigma C^T)[z][x]
  __shared__ float PCtT[DY][36];
  __shared__ float KgT[DY][36];
  __shared__ __align__(16) float mu[DZ];
  __shared__ __align__(16) float muf[DZ];
  __shared__ __align__(16) float Bt[DZ];
  __shared__ float innov[DY], ytl[DY];

  const int i  = tid >> 3;         // 0..31
  const int j0 = (tid & 7) * 4;    // 0,4,..,28

  // init carry
#pragma unroll
  for (int q = 0; q < 4; ++q) Sig[i][j0 + q] = (i == j0 + q) ? 20.0f : 0.0f;
  if (tid < DZ) mu[tid] = 0.0f;

  // preload t=0 operands into registers
  float4 pA, pC = make_float4(0.f, 0.f, 0.f, 0.f);
  float  pB = 0.f, pY = 0.f;
  {
    const size_t tb0 = (size_t)b;
    pA = *(const float4*)(As + tb0 * (DZ * DZ) + tid * 4);
    if (tid < 128)      pC = *(const float4*)(Cs + tb0 * (DY * DZ) + tid * 4);
    else if (tid < 160) pB = Bs[tb0 * DZ + (tid - 128)];
    else if (tid < 176) pY = yin[(size_t)b * TT * DY + (tid - 160)];
  }

  for (int t = 0; t < TT; ++t) {
    const size_t tb = (size_t)t * BB + b;

    // ---- W0: consume prefetch into LDS; store carry outputs; issue prefetch t+1
    *(float4*)&At[i][j0] = pA;
    AtT[j0 + 0][i] = pA.x; AtT[j0 + 1][i] = pA.y;
    AtT[j0 + 2][i] = pA.z; AtT[j0 + 3][i] = pA.w;
    if (tid < 128) {
      int yy = tid >> 3;
      CtT[j0 + 0][yy] = pC.x; CtT[j0 + 1][yy] = pC.y;
      CtT[j0 + 2][yy] = pC.z; CtT[j0 + 3][yy] = pC.w;
    } else if (tid < 160) Bt[tid - 128] = pB;
    else if (tid < 176)   ytl[tid - 160] = pY;

    {
      float4 s4 = *(float4*)&Sig[i][j0];                    // own value (carry)
      *(float4*)(out + OFF_SIGP + tb * (DZ * DZ) + tid * 4) = s4;
      if (tid < DZ) out[OFF_MUP + tb * DZ + tid] = mu[tid];
    }
    {
      int tn = (t + 1 < TT) ? (t + 1) : t;
      size_t tbn = (size_t)tn * BB + b;
      pA = *(const float4*)(As + tbn * (DZ * DZ) + tid * 4);
      if (tid < 128)      pC = *(const float4*)(Cs + tbn * (DY * DZ) + tid * 4);
      else if (tid < 160) pB = Bs[tbn * DZ + (tid - 128)];
      else if (tid < 176) pY = yin[((size_t)b * TT + tn) * DY + (tid - 160)];
    }
    BAR();

    // ---- ph1: PCt = Sigma @ C^T (k split over lane pairs; all 4 waves)
    {
      const int z = tid >> 3, xg = (tid >> 1) & 3, h = tid & 1;
      const int x0 = xg * 4, kb = h * 16;
      float4 acc = make_float4(0.f, 0.f, 0.f, 0.f);
#pragma unroll
      for (int k2 = 0; k2 < 16; ++k2) {
        float s = Sig[z][kb + k2];
        float4 c = *(float4*)&CtT[kb + k2][x0];
        acc.x += s * c.x; acc.y += s * c.y; acc.z += s * c.z; acc.w += s * c.w;
      }
      acc.x += __shfl_xor(acc.x, 1, 64); acc.y += __shfl_xor(acc.y, 1, 64);
      acc.z += __shfl_xor(acc.z, 1, 64); acc.w += __shfl_xor(acc.w, 1, 64);
      if (h == 0) {
        *(float4*)&PCt[z][x0] = acc;
        PCtT[x0 + 0][z] = acc.x; PCtT[x0 + 1][z] = acc.y;
        PCtT[x0 + 2][z] = acc.z; PCtT[x0 + 3][z] = acc.w;
      }
    }
    BAR();

    // ---- ph2+GJ on wave0 (S in registers, shuffle-based pivots); innov on wave1
    if (tid < 64) {
      const int q = tid >> 2, cg = tid & 3, x0 = cg * 4, base = tid & ~3;
      // S = C @ PCt + R, directly into GJ registers (lane (q,cg) = S[q][x0..x0+3])
      float4 w0 = make_float4(0.f, 0.f, 0.f, 0.f);
#pragma unroll 8
      for (int z = 0; z < DZ; ++z) {
        float cv = CtT[z][q];
        float4 pv = *(float4*)&PCt[z][x0];
        w0.x += cv * pv.x; w0.y += cv * pv.y; w0.z += cv * pv.z; w0.w += cv * pv.w;
      }
      w0.x += (q == x0 + 0) ? 0.03f : 0.f;
      w0.y += (q == x0 + 1) ? 0.03f : 0.f;
      w0.z += (q == x0 + 2) ? 0.03f : 0.f;
      w0.w += (q == x0 + 3) ? 0.03f : 0.f;
      float4 w1 = *(float4*)&PCtT[q][x0];
      float4 w2 = *(float4*)&PCtT[q][x0 + 16];
      // 16 pivots, fully unrolled; no LDS round-trips
#pragma unroll
      for (int p = 0; p < 16; ++p) {
        float4 pr0 = shfl4(w0, 4 * p + cg);
        float4 pr1 = shfl4(w1, 4 * p + cg);
        float4 pr2 = shfl4(w2, 4 * p + cg);
        float pp  = __shfl(f4get(w0, p & 3), 4 * p + (p >> 2), 64);
        float wqp = __shfl(f4get(w0, p & 3), base + (p >> 2), 64);
        float m = (q == p) ? 0.f : (wqp * (1.0f / pp));
        w0.x -= m * pr0.x; w0.y -= m * pr0.y; w0.z -= m * pr0.z; w0.w -= m * pr0.w;
        w1.x -= m * pr1.x; w1.y -= m * pr1.y; w1.z -= m * pr1.z; w1.w -= m * pr1.w;
        w2.x -= m * pr2.x; w2.y -= m * pr2.y; w2.z -= m * pr2.z; w2.w -= m * pr2.w;
      }
      // divide by diagonal, write Kg^T
      float4 dblk = shfl4(w0, base + (q >> 2));
      float dq = f4get(dblk, q & 3);
      float di = 1.0f / dq;
      *(float4*)&KgT[q][x0]      = make_float4(w1.x * di, w1.y * di, w1.z * di, w1.w * di);
      *(float4*)&KgT[q][x0 + 16] = make_float4(w2.x * di, w2.y * di, w2.z * di, w2.w * di);
    } else if (tid < 128) {
      // innov = y - C mu (wave1, 4 lanes per y-row)
      const int l = tid - 64, yy = l >> 2, zc = (l & 3) * 8;
      float a = 0.f;
#pragma unroll
      for (int r = 0; r < 8; ++r) a += CtT[zc + r][yy] * mu[zc + r];
      a += __shfl_xor(a, 1, 64);
      a += __shfl_xor(a, 2, 64);
      if ((l & 3) == 0) innov[yy] = ytl[yy] - a;
    }
    BAR();

    // ---- ph5: Sigma_f = Sigma - Kg @ PCt^T (store); mu_f distributed
    {
      float4 acc = *(float4*)&Sig[i][j0];
#pragma unroll
      for (int yy = 0; yy < DY; ++yy) {
        float kg = KgT[yy][i];
        float4 pv = *(float4*)&PCtT[yy][j0];
        acc.x -= kg * pv.x; acc.y -= kg * pv.y; acc.z -= kg * pv.z; acc.w -= kg * pv.w;
      }
      *(float4*)&Sf[i][j0] = acc;
      *(float4*)(out + OFF_SIGF + tb * (DZ * DZ) + tid * 4) = acc;
      if (j0 < 16) {
        float s = 0.f;
#pragma unroll
        for (int r = 0; r < 4; ++r) s += KgT[j0 + r][i] * innov[j0 + r];
        s += __shfl_xor(s, 1, 64);
        s += __shfl_xor(s, 2, 64);
        if ((tid & 3) == 0) muf[i] = mu[i] + s;
      }
    }
    BAR();

    // ---- ph6: M = A_t @ Sigma_f; store mu_f
    {
      float4 acc = make_float4(0.f, 0.f, 0.f, 0.f);
#pragma unroll 8
      for (int k = 0; k < DZ; ++k) {
        float av = At[i][k];
        float4 sv = *(float4*)&Sf[k][j0];
        acc.x += av * sv.x; acc.y += av * sv.y; acc.z += av * sv.z; acc.w += av * sv.w;
      }
      *(float4*)&Mm[i][j0] = acc;
      if (tid < DZ) out[OFF_MUF + tb * DZ + tid] = muf[tid];
    }
    BAR();

    // ---- ph7: Sigma' = M @ A_t^T + Q; mu' = A_t mu_f + B_t (distributed)
    {
      float4 acc = make_float4(0.f, 0.f, 0.f, 0.f);
#pragma unroll 8
      for (int k = 0; k < DZ; ++k) {
        float mv = Mm[i][k];
        float4 av = *(float4*)&AtT[k][j0];
        acc.x += mv * av.x; acc.y += mv * av.y; acc.z += mv * av.z; acc.w += mv * av.w;
      }
      acc.x += (i == j0 + 0) ? 0.08f : 0.f;
      acc.y += (i == j0 + 1) ? 0.08f : 0.f;
      acc.z += (i == j0 + 2) ? 0.08f : 0.f;
      acc.w += (i == j0 + 3) ? 0.08f : 0.f;
      *(float4*)&Sig[i][j0] = acc;

      float4 a4 = *(float4*)&At[i][j0];
      float4 m4 = *(float4*)&muf[j0];
      float s = a4.x * m4.x + a4.y * m4.y + a4.z * m4.z + a4.w * m4.w;
      s += __shfl_xor(s, 1, 64);
      s += __shfl_xor(s, 2, 64);
      s += __shfl_xor(s, 4, 64);
      if ((tid & 7) == 0) mu[i] = Bt[i] + s;
    }
    BAR();
  }
}

extern "C" void kernel_launch(void* const* d_in, const int* in_sizes, int n_in,
                              void* d_out, int out_size, void* d_ws, size_t ws_size,
                              hipStream_t stream) {
  const float* y    = (const float*)d_in[0];
  const float* dist = (const float*)d_in[1];
  const float* A    = (const float*)d_in[2];
  const float* Bm   = (const float*)d_in[3];
  const float* C    = (const float*)d_in[4];
  float* out   = (float*)d_out;
  float* beta0 = (float*)d_ws;   // 256*64 floats

  hipLaunchKernelGGL(alpha_kernel, dim3(BB), dim3(256), 0, stream,
                     dist, out + OFF_ALPHA, beta0);
  hipLaunchKernelGGL(mix_kernel, dim3(TT * BB / 32), dim3(256), 0, stream,
                     A, Bm, C, out + OFF_ALPHA, beta0,
                     out + OFF_AS, out + OFF_BS, out + OFF_CS);
  hipLaunchKernelGGL(kf_kernel, dim3(BB), dim3(256), 0, stream,
                     y, out + OFF_AS, out + OFF_BS, out + OFF_CS, out);
}

// Round 5
// 1260.169 us; speedup vs baseline: 1.1864x; 1.0274x over previous
//
#include <hip/hip_runtime.h>
#include <math.h>

#define TT 128
#define BB 256
#define KC 64
#define DZ 32
#define DY 16

// ---- output layout (float offsets), reference return order ----
#define OFF_MUP   ((size_t)0)
#define OFF_SIGP  (OFF_MUP  + (size_t)TT*BB*DZ)
#define OFF_MUF   (OFF_SIGP + (size_t)TT*BB*DZ*DZ)
#define OFF_SIGF  (OFF_MUF  + (size_t)TT*BB*DZ)
#define OFF_ALPHA (OFF_SIGF + (size_t)TT*BB*DZ*DZ)
#define OFF_AS    (OFF_ALPHA+ (size_t)TT*BB*KC)
#define OFF_BS    (OFF_AS   + (size_t)TT*BB*DZ*DZ)
#define OFF_CS    (OFF_BS   + (size_t)TT*BB*DZ)

typedef __attribute__((ext_vector_type(4))) float f4;
typedef __attribute__((ext_vector_type(8))) short bf16x8;

// raw barrier: LDS visibility only, no vmcnt drain (R2-proven)
#define BAR() do { asm volatile("s_waitcnt lgkmcnt(0)" ::: "memory"); \
                   __builtin_amdgcn_s_barrier(); \
                   asm volatile("" ::: "memory"); } while (0)

__device__ __forceinline__ float wave_max64(float v) {
#pragma unroll
  for (int o = 32; o > 0; o >>= 1) v = fmaxf(v, __shfl_xor(v, o, 64));
  return v;
}
__device__ __forceinline__ float wave_sum64(float v) {
#pragma unroll
  for (int o = 32; o > 0; o >>= 1) v += __shfl_xor(v, o, 64);
  return v;
}
__device__ __forceinline__ f4 shfl4(f4 v, int src) {
  f4 r;
  r.x = __shfl(v.x, src, 64); r.y = __shfl(v.y, src, 64);
  r.z = __shfl(v.z, src, 64); r.w = __shfl(v.w, src, 64);
  return r;
}
__device__ __forceinline__ float f4get(f4 v, int e) {
  return e == 0 ? v.x : (e == 1 ? v.y : (e == 2 ? v.z : v.w));
}
__device__ __forceinline__ float dot4(f4 a, f4 b) {
  return a.x*b.x + a.y*b.y + a.z*b.z + a.w*b.w;
}

// ---------- split-3 bf16 fragments (exact 24-bit decomposition) ----------
struct Frag3 { bf16x8 hi; bf16x8 mid; bf16x8 lo; };

__device__ __forceinline__ short bf16rn(float x) {
  unsigned u = __float_as_uint(x);
  unsigned r = u + 0x7FFFu + ((u >> 16) & 1u);   // round-to-nearest-even
  return (short)(r >> 16);
}
__device__ __forceinline__ float bf2f(short s) {
  return __uint_as_float(((unsigned)(unsigned short)s) << 16);
}
__device__ __forceinline__ Frag3 split8(f4 a, f4 b) {
  Frag3 f;
  float v[8] = {a.x,a.y,a.z,a.w,b.x,b.y,b.z,b.w};
#pragma unroll
  for (int i = 0; i < 8; ++i) {
    float r = v[i];
    short h = bf16rn(r);  r -= bf2f(h);
    short m = bf16rn(r);  r -= bf2f(m);
    short l = bf16rn(r);
    f.hi[i] = h; f.mid[i] = m; f.lo[i] = l;
  }
  return f;
}
// read storage[(l&15)+roff][(l>>4)*8 .. +7]  (K=32 fragment)
__device__ __forceinline__ Frag3 load_frag(const float* base, int ld, int roff, int l) {
  const float* p = base + ((l & 15) + roff) * ld + (l >> 4) * 8;
  return split8(*(const f4*)p, *(const f4*)(p + 4));
}
// K=16 zero-padded fragment (lanes >=32 -> zero), optional sign
__device__ __forceinline__ Frag3 load_frag16(const float* base, int ld, int roff, int l, float sgn) {
  Frag3 f;
  if (l < 32) {
    const float* p = base + ((l & 15) + roff) * ld + (l >> 4) * 8;
    f4 a = *(const f4*)p * sgn;
    f4 b = *(const f4*)(p + 4) * sgn;
    f = split8(a, b);
  } else {
    bf16x8 z = {0,0,0,0,0,0,0,0};
    f.hi = z; f.mid = z; f.lo = z;
  }
  return f;
}
// 6-term product: error ~2^-25 relative (fp32-grade)
__device__ __forceinline__ f4 mfma6(const Frag3& A, const Frag3& B, f4 acc) {
  acc = __builtin_amdgcn_mfma_f32_16x16x32_bf16(A.hi,  B.lo,  acc, 0, 0, 0);
  acc = __builtin_amdgcn_mfma_f32_16x16x32_bf16(A.mid, B.mid, acc, 0, 0, 0);
  acc = __builtin_amdgcn_mfma_f32_16x16x32_bf16(A.lo,  B.hi,  acc, 0, 0, 0);
  acc = __builtin_amdgcn_mfma_f32_16x16x32_bf16(A.hi,  B.mid, acc, 0, 0, 0);
  acc = __builtin_amdgcn_mfma_f32_16x16x32_bf16(A.mid, B.hi,  acc, 0, 0, 0);
  acc = __builtin_amdgcn_mfma_f32_16x16x32_bf16(A.hi,  B.hi,  acc, 0, 0, 0);
  return acc;
}

// ============================================================
// Kernel 1: alpha recursion in LOG space (parallel in t).
// ============================================================
__global__ __launch_bounds__(256) void alpha_kernel(const float* __restrict__ dist,
                                                    float* __restrict__ alphas,
                                                    float* __restrict__ beta0) {
  const int b = blockIdx.x;
  const int w = threadIdx.x >> 6;
  const int lane = threadIdx.x & 63;
  const float* db = dist + (size_t)b * TT * KC;

  __shared__ float ls[TT][KC];
  __shared__ float chT[4][KC];
  __shared__ float l0[KC];

  float csum = 0.f;
  for (int tt = 0; tt < 32; ++tt) {
    int t = w * 32 + tt;
    float d = db[t * KC + lane];
    float m = wave_max64(d);
    float e = expf(d - m);
    float s = wave_sum64(e);
    float lsv = d - m - logf(s);
    ls[t][lane] = lsv;
    csum += lsv;
    if (t == 0) l0[lane] = lsv;
  }
  chT[w][lane] = csum;
  __syncthreads();

  float off = l0[lane];
  for (int w2 = 0; w2 < w; ++w2) off += chT[w2][lane];
  if (threadIdx.x < 64) beta0[b * KC + lane] = expf(l0[lane]);

  float run = off;
  for (int tt = 0; tt < 32; ++tt) {
    int t = w * 32 + tt;
    run += ls[t][lane];
    float m = wave_max64(run);
    float e = expf(run - m);
    float s = wave_sum64(e);
    alphas[((size_t)t * BB + b) * KC + lane] = e / s;
  }
}

// ============================================================
// Kernel 2: batched cluster mixing (f4 alpha reads from LDS).
// ============================================================
__global__ __launch_bounds__(256) void mix_kernel(const float* __restrict__ A,
                                                  const float* __restrict__ Bm,
                                                  const float* __restrict__ C,
                                                  const float* __restrict__ alphas,
                                                  const float* __restrict__ beta0,
                                                  float* __restrict__ As,
                                                  float* __restrict__ Bs,
                                                  float* __restrict__ Cs) {
  const int g   = blockIdx.x;
  const int t   = g >> 3;
  const int b0  = (g & 7) << 5;
  const int tid = threadIdx.x;
  const float* arow = alphas + ((size_t)t * BB + b0) * KC;
  const float* brow = (t > 0) ? (alphas + ((size_t)(t - 1) * BB + b0) * KC)
                              : (beta0 + (size_t)b0 * KC);
  const size_t rbase = (size_t)t * BB + b0;

  __shared__ __align__(16) float aS[32][KC];
  __shared__ __align__(16) float bS[32][KC];
  ((f4*)aS)[tid]       = ((const f4*)arow)[tid];
  ((f4*)aS)[tid + 256] = ((const f4*)arow)[tid + 256];
  ((f4*)bS)[tid]       = ((const f4*)brow)[tid];
  ((f4*)bS)[tid + 256] = ((const f4*)brow)[tid + 256];
  __syncthreads();

  // ---- A mix ----
  {
    const f4* wp = (const f4*)A;            // [64][256] f4
    for (int ch = 0; ch < 2; ++ch) {
      f4 acc[16];
#pragma unroll
      for (int r = 0; r < 16; ++r) acc[r] = (f4){0.f,0.f,0.f,0.f};
      for (int k4 = 0; k4 < 16; ++k4) {
        f4 w0 = wp[(k4*4+0)*256 + tid];
        f4 w1 = wp[(k4*4+1)*256 + tid];
        f4 w2 = wp[(k4*4+2)*256 + tid];
        f4 w3 = wp[(k4*4+3)*256 + tid];
#pragma unroll
        for (int r = 0; r < 16; ++r) {
          f4 a4 = *(const f4*)&aS[ch*16 + r][k4*4];
          acc[r] += a4.x*w0 + a4.y*w1 + a4.z*w2 + a4.w*w3;
        }
      }
#pragma unroll
      for (int r = 0; r < 16; ++r)
        ((f4*)(As + (rbase + ch*16 + r) * (DZ*DZ)))[tid] = acc[r];
    }
  }
  if (tid < 128) {   // ---- C mix (beta) ----
    const f4* wp = (const f4*)C;            // [64][128] f4
    for (int ch = 0; ch < 2; ++ch) {
      f4 acc[16];
#pragma unroll
      for (int r = 0; r < 16; ++r) acc[r] = (f4){0.f,0.f,0.f,0.f};
      for (int k4 = 0; k4 < 16; ++k4) {
        f4 w0 = wp[(k4*4+0)*128 + tid];
        f4 w1 = wp[(k4*4+1)*128 + tid];
        f4 w2 = wp[(k4*4+2)*128 + tid];
        f4 w3 = wp[(k4*4+3)*128 + tid];
#pragma unroll
        for (int r = 0; r < 16; ++r) {
          f4 a4 = *(const f4*)&bS[ch*16 + r][k4*4];
          acc[r] += a4.x*w0 + a4.y*w1 + a4.z*w2 + a4.w*w3;
        }
      }
#pragma unroll
      for (int r = 0; r < 16; ++r)
        ((f4*)(Cs + (rbase + ch*16 + r) * (DY*DZ)))[tid] = acc[r];
    }
  } else if (tid < 192) {   // ---- B mix ----
    const int c = (tid - 128) & 7;
    const f4* wb = (const f4*)Bm;           // [64][8] f4
    for (int ch = 0; ch < 2; ++ch) {
      f4 acc[16];
#pragma unroll
      for (int r = 0; r < 16; ++r) acc[r] = (f4){0.f,0.f,0.f,0.f};
      for (int k4 = 0; k4 < 16; ++k4) {
        f4 w0 = wb[(k4*4+0)*8 + c];
        f4 w1 = wb[(k4*4+1)*8 + c];
        f4 w2 = wb[(k4*4+2)*8 + c];
        f4 w3 = wb[(k4*4+3)*8 + c];
#pragma unroll
        for (int r = 0; r < 16; ++r) {
          f4 a4 = *(const f4*)&aS[ch*16 + r][k4*4];
          acc[r] += a4.x*w0 + a4.y*w1 + a4.z*w2 + a4.w*w3;
        }
      }
#pragma unroll
      for (int r = 0; r < 16; ++r)
        ((f4*)(Bs + (rbase + ch*16 + r) * DZ))[c] = acc[r];
    }
  }
}

// ============================================================
// Kernel 3: Kalman recursion, MFMA split-3-bf16 (fp32-grade).
// 1 block (4 waves) per batch. 3 barriers/step.
//  ph1: w0 PC=Sig*C^T | w1 H=Sig*A^T, G=H^T*A^T | w2 innov + carry stores | w3 staging+prefetch
//  ph2: w0 S=C*PC -> GJ -> Kg | w2 APC=A*PC
//  ph3: w0 muf,mu' | w1 AK=A*Kg, Sig' = G - APC*AK^T + Q | w2 Sigf = Sig - PC*Kg^T (store)
// ============================================================
__global__ __launch_bounds__(256, 1) void kf_kernel(const float* __restrict__ yin,
                                                    const float* __restrict__ As,
                                                    const float* __restrict__ Bs,
                                                    const float* __restrict__ Cs,
                                                    float* __restrict__ out) {
  const int b   = blockIdx.x;
  const int tid = threadIdx.x;
  const int w   = tid >> 6, l = tid & 63;

  __shared__ __align__(16) float Sig[2][DZ][36];
  __shared__ __align__(16) float Af [2][DZ][36];
  __shared__ __align__(16) float Cmx[2][DY][36];
  __shared__ __align__(16) float Btl[2][DZ];
  __shared__ __align__(16) float Ytl[2][DY];
  __shared__ __align__(16) float HT [DZ][36];
  __shared__ __align__(16) float PClds[DZ][20];
  __shared__ __align__(16) float PCtT[DY][36];
  __shared__ __align__(16) float Slds[DY][20];
  __shared__ __align__(16) float KgT[DY][36];
  __shared__ __align__(16) float Kglds[DZ][20];
  __shared__ __align__(16) float APClds[DZ][20];
  __shared__ __align__(16) float AKlds[DZ][20];
  __shared__ __align__(16) float mu[DZ];
  __shared__ __align__(16) float mufs[DZ];
  __shared__ __align__(16) float innov[DY];

  const f4 z4 = {0.f, 0.f, 0.f, 0.f};

  // ---- prologue: stage t=0, init state ----
  {
    size_t t0 = (size_t)b;  // t=0 -> tb = b
    { int e = tid * 4; *(f4*)&Af[0][e >> 5][e & 31] = *(const f4*)(As + t0 * 1024 + e); }
    if (tid < 128) { int e = tid * 4; *(f4*)&Cmx[0][e >> 5][e & 31] = *(const f4*)(Cs + t0 * 512 + e); }
    if (tid < 8)  *(f4*)&Btl[0][tid * 4] = *(const f4*)(Bs + t0 * 32 + tid * 4);
    if (tid < 4)  *(f4*)&Ytl[0][tid * 4] = *(const f4*)(yin + (size_t)b * TT * DY + tid * 4);
    int i = tid >> 3, j0 = (tid & 7) * 4;
#pragma unroll
    for (int q = 0; q < 4; ++q) Sig[0][i][j0 + q] = (i == j0 + q) ? 20.0f : 0.0f;
    if (tid < DZ) mu[tid] = 0.f;
  }
  // prefetch t=1 (wave3 regs)
  f4 pA0, pA1, pA2, pA3, pC0, pC1, pBv, pYv;
  if (w == 3) {
    size_t t1 = (size_t)1 * BB + b;
    pA0 = *(const f4*)(As + t1*1024 + (0*64 + l)*4);
    pA1 = *(const f4*)(As + t1*1024 + (1*64 + l)*4);
    pA2 = *(const f4*)(As + t1*1024 + (2*64 + l)*4);
    pA3 = *(const f4*)(As + t1*1024 + (3*64 + l)*4);
    pC0 = *(const f4*)(Cs + t1*512 + (0*64 + l)*4);
    pC1 = *(const f4*)(Cs + t1*512 + (1*64 + l)*4);
    if (l < 8)              pBv = *(const f4*)(Bs + t1*32 + l*4);
    else if (l < 12)        pYv = *(const f4*)(yin + ((size_t)b*TT + 1)*DY + (l-8)*4);
  }
  __syncthreads();

  for (int t = 0; t < TT; ++t) {
    const int cur = t & 1, nxt = cur ^ 1;
    const size_t tb = (size_t)t * BB + b;
    const int c = l & 15, rg = l >> 4;

    Frag3 f_cB, f_aB0, f_aB1;                   // persist ph1 -> ph2/ph3
    f4 g00 = z4, g01 = z4, g10 = z4, g11 = z4;  // wave1 G accumulator

    // =================== ph1 ===================
    if (w == 0) {
      Frag3 sA0 = load_frag(&Sig[cur][0][0], 36, 0,  l);
      Frag3 sA1 = load_frag(&Sig[cur][0][0], 36, 16, l);
      f_cB      = load_frag(&Cmx[cur][0][0], 36, 0,  l);
      f4 pc0 = mfma6(sA0, f_cB, z4);   // PC rows 0-15
      f4 pc1 = mfma6(sA1, f_cB, z4);   // PC rows 16-31
#pragma unroll
      for (int m = 0; m < 4; ++m) {
        PClds[rg*4 + m][c]      = f4get(pc0, m);
        PClds[16 + rg*4 + m][c] = f4get(pc1, m);
      }
      *(f4*)&PCtT[c][rg*4]      = pc0;
      *(f4*)&PCtT[c][16 + rg*4] = pc1;
    } else if (w == 1) {
      Frag3 gA0 = load_frag(&Sig[cur][0][0], 36, 0,  l);
      Frag3 gA1 = load_frag(&Sig[cur][0][0], 36, 16, l);
      f_aB0 = load_frag(&Af[cur][0][0], 36, 0,  l);
      f_aB1 = load_frag(&Af[cur][0][0], 36, 16, l);
      f4 h00 = mfma6(gA0, f_aB0, z4);
      f4 h01 = mfma6(gA0, f_aB1, z4);
      f4 h10 = mfma6(gA1, f_aB0, z4);
      f4 h11 = mfma6(gA1, f_aB1, z4);
      // publish H transposed: HT[j][i] = H[i][j]
      *(f4*)&HT[c][rg*4]           = h00;
      *(f4*)&HT[16 + c][rg*4]      = h01;
      *(f4*)&HT[c][16 + rg*4]      = h10;
      *(f4*)&HT[16 + c][16 + rg*4] = h11;
      Frag3 hA0 = load_frag(&HT[0][0], 36, 0,  l);
      Frag3 hA1 = load_frag(&HT[0][0], 36, 16, l);
      g00 = mfma6(hA0, f_aB0, z4);  g01 = mfma6(hA0, f_aB1, z4);
      g10 = mfma6(hA1, f_aB0, z4);  g11 = mfma6(hA1, f_aB1, z4);
    } else if (w == 2) {
      // innov = y - C*mu
      int yy = l >> 2, p = l & 3, k0 = p * 8;
      f4 c0 = *(const f4*)&Cmx[cur][yy][k0], c1 = *(const f4*)&Cmx[cur][yy][k0 + 4];
      f4 m0 = *(const f4*)&mu[k0],           m1 = *(const f4*)&mu[k0 + 4];
      float a = dot4(c0, m0) + dot4(c1, m1);
      a += __shfl_xor(a, 1, 64);
      a += __shfl_xor(a, 2, 64);
      if (p == 0) innov[yy] = Ytl[cur][yy] - a;
      // store Sigma_pred / mu_pred (carry)
#pragma unroll
      for (int m = 0; m < 4; ++m) {
        int e = (m*64 + l) * 4;
        f4 v = *(const f4*)&Sig[cur][e >> 5][e & 31];
        *(f4*)(out + OFF_SIGP + tb * 1024 + e) = v;
      }
      if (l < DZ) out[OFF_MUP + tb * DZ + l] = mu[l];
    } else {
      // staging buf[nxt] = t+1 data (from prefetch regs)
      { int e = (0*64 + l)*4; *(f4*)&Af[nxt][e >> 5][e & 31] = pA0; }
      { int e = (1*64 + l)*4; *(f4*)&Af[nxt][e >> 5][e & 31] = pA1; }
      { int e = (2*64 + l)*4; *(f4*)&Af[nxt][e >> 5][e & 31] = pA2; }
      { int e = (3*64 + l)*4; *(f4*)&Af[nxt][e >> 5][e & 31] = pA3; }
      { int e = (0*64 + l)*4; *(f4*)&Cmx[nxt][e >> 5][e & 31] = pC0; }
      { int e = (1*64 + l)*4; *(f4*)&Cmx[nxt][e >> 5][e & 31] = pC1; }
      if (l < 8)       *(f4*)&Btl[nxt][l*4] = pBv;
      else if (l < 12) *(f4*)&Ytl[nxt][(l-8)*4] = pYv;
      // issue prefetch for t+2
      int tf = (t + 2 < TT) ? (t + 2) : (TT - 1);
      size_t tbf = (size_t)tf * BB + b;
      pA0 = *(const f4*)(As + tbf*1024 + (0*64 + l)*4);
      pA1 = *(const f4*)(As + tbf*1024 + (1*64 + l)*4);
      pA2 = *(const f4*)(As + tbf*1024 + (2*64 + l)*4);
      pA3 = *(const f4*)(As + tbf*1024 + (3*64 + l)*4);
      pC0 = *(const f4*)(Cs + tbf*512 + (0*64 + l)*4);
      pC1 = *(const f4*)(Cs + tbf*512 + (1*64 + l)*4);
      if (l < 8)       pBv = *(const f4*)(Bs + tbf*32 + l*4);
      else if (l < 12) pYv = *(const f4*)(yin + ((size_t)b*TT + tf)*DY + (l-8)*4);
    }
    BAR();

    // =================== ph2 ===================
    if (w == 0) {
      // S = C*PC + R
      Frag3 pB = load_frag(&PCtT[0][0], 36, 0, l);
      f4 s = mfma6(f_cB, pB, z4);
#pragma unroll
      for (int m = 0; m < 4; ++m)
        Slds[rg*4 + m][c] = f4get(s, m) + ((rg*4 + m) == c ? 0.03f : 0.f);
      // GJ on [S | PC^T] (R2-proven register/shuffle version)
      const int q = l >> 2, cg = l & 3, base = l & ~3;
      f4 w0 = *(const f4*)&Slds[q][cg*4];
      f4 w1 = *(const f4*)&PCtT[q][cg*4];
      f4 w2 = *(const f4*)&PCtT[q][16 + cg*4];
#pragma unroll
      for (int p = 0; p < 16; ++p) {
        f4 pr0 = shfl4(w0, 4*p + cg);
        f4 pr1 = shfl4(w1, 4*p + cg);
        f4 pr2 = shfl4(w2, 4*p + cg);
        float pp  = __shfl(f4get(w0, p & 3), 4*p + (p >> 2), 64);
        float wqp = __shfl(f4get(w0, p & 3), base + (p >> 2), 64);
        float m = (q == p) ? 0.f : (wqp * (1.0f / pp));
        w0 -= m * pr0; w1 -= m * pr1; w2 -= m * pr2;
      }
      f4 dblk = shfl4(w0, base + (q >> 2));
      float di = 1.0f / f4get(dblk, q & 3);
      f4 w1d = w1 * di, w2d = w2 * di;
      *(f4*)&KgT[q][cg*4]      = w1d;
      *(f4*)&KgT[q][16 + cg*4] = w2d;
#pragma unroll
      for (int e = 0; e < 4; ++e) {
        Kglds[cg*4 + e][q]      = f4get(w1d, e);
        Kglds[16 + cg*4 + e][q] = f4get(w2d, e);
      }
    } else if (w == 2) {
      // APC = A*PC
      Frag3 aA0 = load_frag(&Af[cur][0][0], 36, 0,  l);
      Frag3 aA1 = load_frag(&Af[cur][0][0], 36, 16, l);
      Frag3 pcB = load_frag(&PCtT[0][0], 36, 0, l);
      f4 ap0 = mfma6(aA0, pcB, z4);
      f4 ap1 = mfma6(aA1, pcB, z4);
#pragma unroll
      for (int m = 0; m < 4; ++m) {
        APClds[rg*4 + m][c]      = f4get(ap0, m);
        APClds[16 + rg*4 + m][c] = f4get(ap1, m);
      }
    }
    BAR();

    // =================== ph3 ===================
    if (w == 0) {
      if (l < DZ) {
        float a = mu[l];
#pragma unroll
        for (int y = 0; y < DY; ++y) a += KgT[y][l] * innov[y];
        mufs[l] = a;
        out[OFF_MUF + tb * DZ + l] = a;
      }
      // mu' = A*muf + B
      int i = l >> 1, h = l & 1, k0 = h * 16;
      f4 a0 = *(const f4*)&Af[cur][i][k0],     a1 = *(const f4*)&Af[cur][i][k0 + 4];
      f4 a2 = *(const f4*)&Af[cur][i][k0 + 8], a3 = *(const f4*)&Af[cur][i][k0 + 12];
      f4 m0 = *(const f4*)&mufs[k0],     m1 = *(const f4*)&mufs[k0 + 4];
      f4 m2 = *(const f4*)&mufs[k0 + 8], m3 = *(const f4*)&mufs[k0 + 12];
      float s = dot4(a0,m0) + dot4(a1,m1) + dot4(a2,m2) + dot4(a3,m3);
      s += __shfl_xor(s, 1, 64);
      if (h == 0) mu[i] = s + Btl[cur][i];
    } else if (w == 1) {
      // AK = A*Kg
      Frag3 kB = load_frag(&KgT[0][0], 36, 0, l);
      f4 ak0 = mfma6(f_aB0, kB, z4);
      f4 ak1 = mfma6(f_aB1, kB, z4);
#pragma unroll
      for (int m = 0; m < 4; ++m) {
        AKlds[rg*4 + m][c]      = f4get(ak0, m);
        AKlds[16 + rg*4 + m][c] = f4get(ak1, m);
      }
      // Sig' = G - APC*AK^T + Q
      Frag3 apA0 = load_frag16(&APClds[0][0], 20, 0,  l,  1.f);
      Frag3 apA1 = load_frag16(&APClds[0][0], 20, 16, l,  1.f);
      Frag3 akB0 = load_frag16(&AKlds[0][0],  20, 0,  l, -1.f);
      Frag3 akB1 = load_frag16(&AKlds[0][0],  20, 16, l, -1.f);
      g00 = mfma6(apA0, akB0, g00);  g01 = mfma6(apA0, akB1, g01);
      g10 = mfma6(apA1, akB0, g10);  g11 = mfma6(apA1, akB1, g11);
#pragma unroll
      for (int m = 0; m < 4; ++m) {
        if (rg*4 + m == c) { g00[m] += 0.08f; g11[m] += 0.08f; }
      }
      *(f4*)&Sig[nxt][c][rg*4]           = g00;
      *(f4*)&Sig[nxt][16 + c][rg*4]      = g01;
      *(f4*)&Sig[nxt][c][16 + rg*4]      = g10;
      *(f4*)&Sig[nxt][16 + c][16 + rg*4] = g11;
    } else if (w == 2) {
      // Sigf = Sig - PC*Kg^T  (symmetric; store via transposed tiles)
      Frag3 pA0  = load_frag16(&PClds[0][0], 20, 0,  l,  1.f);
      Frag3 pA1  = load_frag16(&PClds[0][0], 20, 16, l,  1.f);
      Frag3 kgB0 = load_frag16(&Kglds[0][0], 20, 0,  l, -1.f);
      Frag3 kgB1 = load_frag16(&Kglds[0][0], 20, 16, l, -1.f);
      f4 sf00 = *(const f4*)&Sig[cur][c][rg*4];
      f4 sf01 = *(const f4*)&Sig[cur][16 + c][rg*4];
      f4 sf10 = *(const f4*)&Sig[cur][c][16 + rg*4];
      f4 sf11 = *(const f4*)&Sig[cur][16 + c][16 + rg*4];
      sf00 = mfma6(pA0, kgB0, sf00);  sf01 = mfma6(pA0, kgB1, sf01);
      sf10 = mfma6(pA1, kgB0, sf10);  sf11 = mfma6(pA1, kgB1, sf11);
      float* o = out + OFF_SIGF + tb * 1024;
      *(f4*)(o + (c)*32 + rg*4)             = sf00;
      *(f4*)(o + (16 + c)*32 + rg*4)        = sf01;
      *(f4*)(o + (c)*32 + 16 + rg*4)        = sf10;
      *(f4*)(o + (16 + c)*32 + 16 + rg*4)   = sf11;
    }
    BAR();
  }
}

extern "C" void kernel_launch(void* const* d_in, const int* in_sizes, int n_in,
                              void* d_out, int out_size, void* d_ws, size_t ws_size,
                              hipStream_t stream) {
  const float* y    = (const float*)d_in[0];
  const float* dist = (const float*)d_in[1];
  const float* A    = (const float*)d_in[2];
  const float* Bm   = (const float*)d_in[3];
  const float* C    = (const float*)d_in[4];
  float* out   = (float*)d_out;
  float* beta0 = (float*)d_ws;

  hipLaunchKernelGGL(alpha_kernel, dim3(BB), dim3(256), 0, stream,
                     dist, out + OFF_ALPHA, beta0);
  hipLaunchKernelGGL(mix_kernel, dim3(TT * BB / 32), dim3(256), 0, stream,
                     A, Bm, C, out + OFF_ALPHA, beta0,
                     out + OFF_AS, out + OFF_BS, out + OFF_CS);
  hipLaunchKernelGGL(kf_kernel, dim3(BB), dim3(256), 0, stream,
                     y, out + OFF_AS, out + OFF_BS, out + OFF_CS, out);
}